// Round 5
// baseline (32591.058 us; speedup 1.0000x reference)
//
#include <hip/hip_runtime.h>
#include <hip/hip_cooperative_groups.h>
#include <math.h>

namespace cg = cooperative_groups;

constexpr int kB = 64, kS = 24, kT = 96, kE = 256, kH = 512, kA = 512;
constexpr int NWG = 256, NTH = 512;  // 4 groups x 64 WGs, 1 WG/CU
constexpr int GB = 16;  // batches per group
constexpr int HC = 8;   // h-cols per WG
constexpr int GC = 32;  // gate cols per WG
constexpr int HP = 516; // padded LDS row stride

// ws layout (floats). pub: [2 parity][4 gb][64 m][128], linear in (m,b,hcl).
constexpr int OFF_PUB = 0;
constexpr int OFF_SH  = OFF_PUB + 2 * kB * kH;
constexpr int OFF_HS  = OFF_SH + 2 * kB * kH;
constexpr int OFF_Z   = OFF_HS + kB * kT * kH;
constexpr int OFF_CTX = OFF_Z + kB * kT;
constexpr int OFF_SHS = OFF_CTX + kB * kH;
constexpr int OFF_Z2  = OFF_SHS + kB * kS * kH;
constexpr int OFF_FLG = (OFF_Z2 + kB * kS + 31) & ~31;  // [4 gb][64 m] * 32 uints

__device__ __forceinline__ float sigmoidf(float x) { return 1.0f / (1.0f + expf(-x)); }
__device__ __forceinline__ float dot4(float4 a, float4 b) {
  return a.x * b.x + a.y * b.y + a.z * b.z + a.w * b.w;
}
__device__ __forceinline__ float2 aload2(const float* p) {
  unsigned long long u = __hip_atomic_load((const unsigned long long*)p,
                                           __ATOMIC_RELAXED, __HIP_MEMORY_SCOPE_AGENT);
  union { unsigned long long u; float2 f; } cv; cv.u = u;
  return cv.f;
}
__device__ __forceinline__ float aload1(const float* p) {
  return __hip_atomic_load(p, __ATOMIC_RELAXED, __HIP_MEMORY_SCOPE_AGENT);
}
__device__ __forceinline__ void astore(float* p, float v) {
  __hip_atomic_store(p, v, __ATOMIC_RELAXED, __HIP_MEMORY_SCOPE_AGENT);
}
__device__ __forceinline__ void astore2(float* p, float a, float b) {
  union { float2 f; unsigned long long u; } cv;
  cv.f = make_float2(a, b);
  __hip_atomic_store((unsigned long long*)p, cv.u, __ATOMIC_RELAXED,
                     __HIP_MEMORY_SCOPE_AGENT);
}
__device__ __forceinline__ unsigned aloadu(const unsigned* p) {
  return __hip_atomic_load(p, __ATOMIC_RELAXED, __HIP_MEMORY_SCOPE_AGENT);
}

__global__ __launch_bounds__(NTH) void ha_kernel(
    const int* __restrict__ captions, const int* __restrict__ masks,
    const float* __restrict__ embed_W,
    const float* __restrict__ w_Wih, const float* __restrict__ w_Whh,
    const float* __restrict__ w_bih, const float* __restrict__ w_bhh,
    const float* __restrict__ s_Wih, const float* __restrict__ s_Whh,
    const float* __restrict__ s_bih, const float* __restrict__ s_bhh,
    const float* __restrict__ wa_Wk, const float* __restrict__ wa_Wv,
    const float* __restrict__ sa_Wk, const float* __restrict__ sa_Wv,
    float* __restrict__ out, float* __restrict__ ws) {
  cg::grid_group grid = cg::this_grid();
  const int g = blockIdx.x, tid = threadIdx.x;
  const int gb = g & 3, gm = g >> 2;   // group (4), member (64)
  const int B0 = GB * gb;
  const int hc0 = HC * gm;
  const int jj = tid >> 6;
  const int lane = tid & 63, cc = lane >> 3, bp = lane & 7;
  const int b0 = 2 * bp, b1 = b0 + 1;

  float* pub = ws + OFF_PUB;
  float* sh_buf = ws + OFF_SH;
  float* hs_buf = ws + OFF_HS;
  float* z_buf = ws + OFF_Z;
  float* ctx_ws = ws + OFF_CTX;
  float* sent_hs = ws + OFF_SHS;
  float* z2_buf = ws + OFF_Z2;
  unsigned* flags = (unsigned*)(ws + OFF_FLG);
  unsigned* myflag = &flags[(gb * 64 + gm) * 32];

  // LDS ~150.7 KB, 1 WG/CU
  __shared__ __align__(16) float whh_s[GC][HP];   // LDS-resident Whh slice (66 KB)
  __shared__ float bias_s[GC];
  __shared__ __align__(16) float hstage[GB][HP];  // h tile; aliased by attn/sent staging
  __shared__ __align__(16) float part_f[8 * 576];
  __shared__ __align__(16) float stash[48 * 128]; // hs values, dumped 2x/sentence
  __shared__ int masks_s[GB * kT];
  __shared__ float c_s[HC][GB], hown_s[HC][GB], sc_s[HC][GB];
  __shared__ float soft_s[kT], red_s[96];

  float (*h_s)[HP] = reinterpret_cast<float (*)[HP]>(&hstage[0][0]);
  float* attn_f = &hstage[0][0];

  auto grow = [&](int c) { return (c >> 3) * kH + hc0 + (c & 7); };

  // ---- init ----
  for (int idx = tid; idx < GC * kH; idx += NTH) {
    int r = idx >> 9, k = idx & (kH - 1);
    int c_log = 4 * (r & 7) + (r >> 3);
    whh_s[r][k] = w_Whh[(size_t)grow(c_log) * kH + k];
  }
  if (tid < GC) bias_s[tid] = w_bih[grow(tid)] + w_bhh[grow(tid)];
  if (tid < HC * GB) {
    c_s[tid >> 4][tid & 15] = 0.f;
    hown_s[tid >> 4][tid & 15] = 0.f;
    sc_s[tid >> 4][tid & 15] = 0.f;
  }
  for (int idx = tid; idx < GB * HP; idx += NTH) hstage[idx / HP][idx % HP] = 0.f;
  {
    int idx = g * NTH + tid;   // pub (65536) + sh (65536)
    if (idx < 2 * kB * kH) pub[idx] = 0.f;
    else sh_buf[idx - 2 * kB * kH] = 0.f;
  }
  if (g == 0)
    for (int idx = tid; idx < 4 * 64 * 32; idx += NTH) flags[idx] = 0u;
  grid.sync();

  // arrive: per-WG-line atomicAdd (parallel across WGs, RMW executes at the
  // coherence point -> promptly visible). wait: 64 threads poll 64 lines.
  auto wait_flags = [&](unsigned nn) {
    if (tid < 64) {
      while (aloadu(&flags[(gb * 64 + tid) * 32]) < nn) __builtin_amdgcn_s_sleep(1);
    }
    __syncthreads();
  };

  // stage pub slab -> rotated hstage (coalesced global read).
  auto stage_pub = [&](const float* slab) {
#pragma unroll
    for (int it = 0; it < 8; ++it) {
      const int lin = it * 1024 + tid * 2;
      const int k = ((lin >> 7) << 3) | (lin & 7);
      const int b = (lin >> 3) & 15;
      float2 v = aload2(&slab[lin]);
      const int ch = (((k >> 2) + (b >> 1)) & 127) * 4 + (k & 3);
      *(float2*)&h_s[b][ch] = v;
    }
  };

  // K1 linear stager (ctx / sh in the sentence phase)
  auto stage16_lin = [&](const float* src) {
#pragma unroll
    for (int r = 0; r < 8; ++r) {
      const int f = (r * 512 + tid) * 2;
      const int b = f >> 9, k = f & (kH - 1);
      float2 v = aload2(src + b * kH + k);
      const int ch = (((k >> 2) + (b >> 1)) & 127) * 4 + (k & 3);
      *(float2*)&h_s[b][ch] = v;
    }
  };

  // dump stash rows [0,48) -> hs_buf[t = tbase..tbase+47]
  auto dump_stash = [&](int tbase) {
    for (int p = tid; p < 768; p += NTH) {
      const int t2 = p >> 4, b = p & 15;
      float v[8];
#pragma unroll
      for (int h = 0; h < 8; ++h) v[h] = stash[t2 * 128 + h * 16 + b];
      float* dst = &hs_buf[((size_t)(B0 + b) * kT + tbase + t2) * kH + hc0];
      astore2(dst + 0, v[0], v[1]);
      astore2(dst + 2, v[2], v[3]);
      astore2(dst + 4, v[4], v[5]);
      astore2(dst + 6, v[6], v[7]);
    }
  };

  float xp[4][2];
  auto prefetch = [&](int s2, int t2) {
    const int cap0 = captions[((B0 + b0) * kS + s2) * kT + t2];
    const int cap1 = captions[((B0 + b1) * kS + s2) * kT + t2];
    const float4* __restrict__ x0 = (const float4*)(embed_W + (size_t)cap0 * kE);
    const float4* __restrict__ x1 = (const float4*)(embed_W + (size_t)cap1 * kE);
#pragma unroll
    for (int d = 0; d < 4; ++d) { xp[d][0] = 0.f; xp[d][1] = 0.f; }
#pragma unroll 2
    for (int u = 0; u < 8; ++u) {
      const int ec = 8 * jj + u;
      const float4 xv0 = x0[ec], xv1 = x1[ec];
#pragma unroll
      for (int d = 0; d < 4; ++d) {
        const float4 w = *(const float4*)&w_Wih[(size_t)grow(4 * cc + d) * kE + 4 * ec];
        xp[d][0] += dot4(w, xv0);
        xp[d][1] += dot4(w, xv1);
      }
    }
  };

  prefetch(0, 0);
  unsigned n = 0;
  int gstep = 0;
  for (int s = 0; s < kS; ++s) {
    // per-sentence: masks to LDS; restage h from pub (phases clobbered hstage)
    for (int idx = tid; idx < GB * kT; idx += NTH)
      masks_s[idx] = masks[((B0 + idx / kT) * kS + s) * kT + (idx % kT)];
    if (s > 0) stage_pub(pub + ((size_t)(gstep & 1) * 4 + gb) * 8192);
    __syncthreads();

    // ================= word LSTM: 96 steps, one barrier each =================
    for (int t = 0; t < kT; ++t, ++gstep) {
      float* pubw = pub + ((size_t)((gstep + 1) & 1) * 4 + gb) * 8192;

      // GEMV (rotated layout, conflict-free)
      float acc[4][2];
#pragma unroll
      for (int d = 0; d < 4; ++d) { acc[d][0] = xp[d][0]; acc[d][1] = xp[d][1]; }
#pragma unroll 4
      for (int u = 0; u < 16; ++u) {
        const int chunk = 16 * jj + u;
        const int offW = chunk * 4;
        const int offH = ((chunk + bp) & 127) * 4;
        const float4 h0v = *(const float4*)&h_s[b0][offH];
        const float4 h1v = *(const float4*)&h_s[b1][offH];
#pragma unroll
        for (int d = 0; d < 4; ++d) {
          const float4 w = *(const float4*)&whh_s[d * 8 + cc][offW];
          acc[d][0] += dot4(w, h0v);
          acc[d][1] += dot4(w, h1v);
        }
      }
#pragma unroll
      for (int d = 0; d < 4; ++d) {
        part_f[jj * 576 + lane * 9 + d * 2 + 0] = acc[d][0];
        part_f[jj * 576 + lane * 9 + d * 2 + 1] = acc[d][1];
      }
      __syncthreads();
      // fused reduce + cell (tid<128): sum 4 gates, cell, publish, stash
      if (tid < HC * GB) {
        const int hcl = tid >> 4, b = tid & 15;
        float gg4[4];
#pragma unroll
        for (int g2 = 0; g2 < 4; ++g2) {
          const int c = g2 * 8 + hcl;
          const int lp = (c >> 2) * 8 + (b >> 1), sl = (c & 3) * 2 + (b & 1);
          float sum = bias_s[c];
#pragma unroll
          for (int j = 0; j < 8; ++j) sum += part_f[j * 576 + lp * 9 + sl];
          gg4[g2] = sum;
        }
        const float cold = c_s[hcl][b];
        const float c2 = sigmoidf(gg4[1]) * cold + sigmoidf(gg4[0]) * tanhf(gg4[2]);
        const float h2 = sigmoidf(gg4[3]) * tanhf(c2);
        const int m = masks_s[b * kT + t];
        const float cn = m ? c2 : cold;
        const float hn = m ? h2 : hown_s[hcl][b];
        c_s[hcl][b] = cn;
        hown_s[hcl][b] = hn;
        astore(&pubw[gm * 128 + b * 8 + hcl], hn);  // 512B/WG, 4 full lines
        stash[(t % 48) * 128 + tid] = m ? h2 : 0.f;
      }
      ++n;
      __syncthreads();                        // drains publish; orders stash
      if (tid == 0) atomicAdd(myflag, 1u);    // arrive (prompt, parallel lines)
      // cover work during flag propagation:
      if (t == 47) dump_stash(0);
      else if (t == kT - 1) dump_stash(48);
      if (t < kT - 1) prefetch(s, t + 1);
      wait_flags(n);
      stage_pub(pubw);
      __syncthreads();
    }

    // phase barrier (drains stash dumps before attention reads)
    ++n;
    __syncthreads();
    if (tid == 0) atomicAdd(myflag, 1u);
    wait_flags(n);

    // ================= word attention: z[b,t] (group-local) =================
    {
      const int ab = gm >> 2, at0 = (gm & 3) * 24;
      const int bg = B0 + ab;
      for (int half = 0; half < 2; ++half) {
        const int tb = at0 + half * 12;
        for (int idx = tid; idx < 12 * 256; idx += NTH) {
          int pp = idx >> 8, hh2 = (idx & 255) * 2;
          float2 v = aload2(&hs_buf[((size_t)bg * kT + tb + pp) * kH + hh2]);
          *(float2*)&attn_f[pp * HP + hh2] = v;
        }
        __syncthreads();
        const int aa = tid;
        float dacc[12];
#pragma unroll
        for (int p = 0; p < 12; ++p) dacc[p] = 0.f;
        const float4* __restrict__ wk = (const float4*)(wa_Wk + (size_t)aa * kH);
        for (int k = 0; k < kH / 4; ++k) {
          float4 w = wk[k];
#pragma unroll
          for (int p = 0; p < 12; ++p)
            dacc[p] += dot4(w, *(const float4*)&attn_f[p * HP + k * 4]);
        }
        const float wv = wa_Wv[aa];
        const int ln = tid & 63, wid = tid >> 6;
#pragma unroll
        for (int p = 0; p < 12; ++p) {
          float v = wv * tanhf(dacc[p]);
          v += __shfl_down(v, 32); v += __shfl_down(v, 16); v += __shfl_down(v, 8);
          v += __shfl_down(v, 4);  v += __shfl_down(v, 2);  v += __shfl_down(v, 1);
          if (ln == 0) red_s[wid * 12 + p] = v;
        }
        __syncthreads();
        if (tid < 12) {
          float sum = 0.f;
#pragma unroll
          for (int w = 0; w < 8; ++w) sum += red_s[w * 12 + tid];
          astore(&z_buf[bg * kT + tb + tid], sum);
        }
        __syncthreads();
      }
    }
    ++n;
    __syncthreads();
    if (tid == 0) atomicAdd(myflag, 1u);
    wait_flags(n);

    // ================= softmax over T + ctx =================
    if (gm < GB) {
      const int b = B0 + gm;
      if (tid < kT) soft_s[tid] = aload1(&z_buf[b * kT + tid]);
      __syncthreads();
      float mx = -1e30f;
      for (int i = 0; i < kT; ++i) mx = fmaxf(mx, soft_s[i]);
      float den = 0.f;
      for (int i = 0; i < kT; ++i) den += expf(soft_s[i] - mx);
      __syncthreads();
      if (tid < kT) soft_s[tid] = expf(soft_s[tid] - mx) / den;
      __syncthreads();
      {
        const int h0 = tid;
        float a0 = 0.f, a1 = 0.f, a2 = 0.f, a3 = 0.f;
        for (int tt = 0; tt < kT; tt += 4) {
          a0 += soft_s[tt + 0] * aload1(&hs_buf[((size_t)b * kT + tt + 0) * kH + h0]);
          a1 += soft_s[tt + 1] * aload1(&hs_buf[((size_t)b * kT + tt + 1) * kH + h0]);
          a2 += soft_s[tt + 2] * aload1(&hs_buf[((size_t)b * kT + tt + 2) * kH + h0]);
          a3 += soft_s[tt + 3] * aload1(&hs_buf[((size_t)b * kT + tt + 3) * kH + h0]);
        }
        astore(&ctx_ws[b * kH + h0], (a0 + a1) + (a2 + a3));
      }
    }
    ++n;
    __syncthreads();
    if (tid == 0) atomicAdd(myflag, 1u);
    wait_flags(n);

    // ================= sentence LSTM (two-pass GEMV) =================
    {
      float acc[4][2];
#pragma unroll
      for (int d = 0; d < 4; ++d) { acc[d][0] = 0.f; acc[d][1] = 0.f; }
      stage16_lin(ctx_ws + B0 * kH);  // pass A: x = ctx
      __syncthreads();
#pragma unroll 2
      for (int u = 0; u < 16; ++u) {
        const int chunk = 16 * jj + u;
        const int offH = ((chunk + bp) & 127) * 4;
        const float4 x0v = *(const float4*)&h_s[b0][offH];
        const float4 x1v = *(const float4*)&h_s[b1][offH];
#pragma unroll
        for (int d = 0; d < 4; ++d) {
          const float4 w = *(const float4*)&s_Wih[(size_t)grow(4 * cc + d) * kH + chunk * 4];
          acc[d][0] += dot4(w, x0v);
          acc[d][1] += dot4(w, x1v);
        }
      }
      __syncthreads();
      stage16_lin(sh_buf + (s & 1) * kB * kH + B0 * kH);  // pass B: h = sh
      __syncthreads();
#pragma unroll 2
      for (int u = 0; u < 16; ++u) {
        const int chunk = 16 * jj + u;
        const int offH = ((chunk + bp) & 127) * 4;
        const float4 h0v = *(const float4*)&h_s[b0][offH];
        const float4 h1v = *(const float4*)&h_s[b1][offH];
#pragma unroll
        for (int d = 0; d < 4; ++d) {
          const float4 w = *(const float4*)&s_Whh[(size_t)grow(4 * cc + d) * kH + chunk * 4];
          acc[d][0] += dot4(w, h0v);
          acc[d][1] += dot4(w, h1v);
        }
      }
#pragma unroll
      for (int d = 0; d < 4; ++d) {
        part_f[jj * 576 + lane * 9 + d * 2 + 0] = acc[d][0];
        part_f[jj * 576 + lane * 9 + d * 2 + 1] = acc[d][1];
      }
      __syncthreads();
      if (tid < HC * GB) {
        const int hcl = tid >> 4, b = tid & 15;
        float gg4[4];
#pragma unroll
        for (int g2 = 0; g2 < 4; ++g2) {
          const int c = g2 * 8 + hcl;
          const int lp = (c >> 2) * 8 + (b >> 1), sl = (c & 3) * 2 + (b & 1);
          const int row = grow(c);
          float sum = s_bih[row] + s_bhh[row];
#pragma unroll
          for (int j = 0; j < 8; ++j) sum += part_f[j * 576 + lp * 9 + sl];
          gg4[g2] = sum;
        }
        const float c2 = sigmoidf(gg4[1]) * sc_s[hcl][b] + sigmoidf(gg4[0]) * tanhf(gg4[2]);
        const float h2 = sigmoidf(gg4[3]) * tanhf(c2);
        sc_s[hcl][b] = c2;
        const int col = hc0 + hcl;
        astore(&sh_buf[((s + 1) & 1) * kB * kH + (B0 + b) * kH + col], h2);
        astore(&sent_hs[((size_t)(B0 + b) * kS + s) * kH + col], h2);
      }
    }
    ++n;
    __syncthreads();
    if (tid == 0) atomicAdd(myflag, 1u);
    if (s < kS - 1) prefetch(s + 1, 0);
    wait_flags(n);
  }

  // ================= final attention over S (group-local) =================
  {
    const int pair0 = gm * 6;
    for (int idx = tid; idx < 6 * 256; idx += NTH) {
      int pp = idx >> 8, hh2 = (idx & 255) * 2;
      const int pr = pair0 + pp;
      float2 v = aload2(&sent_hs[((size_t)(B0 + pr / kS) * kS + pr % kS) * kH + hh2]);
      *(float2*)&attn_f[pp * HP + hh2] = v;
    }
    __syncthreads();
    const int aa = tid;
    float dacc[6];
#pragma unroll
    for (int p = 0; p < 6; ++p) dacc[p] = 0.f;
    const float4* __restrict__ wk = (const float4*)(sa_Wk + (size_t)aa * kH);
    for (int k = 0; k < kH / 4; ++k) {
      float4 w = wk[k];
#pragma unroll
      for (int p = 0; p < 6; ++p)
        dacc[p] += dot4(w, *(const float4*)&attn_f[p * HP + k * 4]);
    }
    const float wv = sa_Wv[aa];
    const int ln = tid & 63, wid = tid >> 6;
#pragma unroll
    for (int p = 0; p < 6; ++p) {
      float v = wv * tanhf(dacc[p]);
      v += __shfl_down(v, 32); v += __shfl_down(v, 16); v += __shfl_down(v, 8);
      v += __shfl_down(v, 4);  v += __shfl_down(v, 2);  v += __shfl_down(v, 1);
      if (ln == 0) red_s[wid * 6 + p] = v;
    }
    __syncthreads();
    if (tid < 6) {
      float sum = 0.f;
#pragma unroll
      for (int w = 0; w < 8; ++w) sum += red_s[w * 6 + tid];
      astore(&z2_buf[B0 * kS + pair0 + tid], sum);
    }
  }
  ++n;
  __syncthreads();
  if (tid == 0) atomicAdd(myflag, 1u);
  wait_flags(n);

  // ================= final softmax + outputs =================
  if (gm < GB) {
    const int b = B0 + gm;
    if (tid < kS) soft_s[tid] = aload1(&z2_buf[b * kS + tid]);
    __syncthreads();
    float mx = -1e30f;
    for (int i = 0; i < kS; ++i) mx = fmaxf(mx, soft_s[i]);
    float den = 0.f;
    for (int i = 0; i < kS; ++i) den += expf(soft_s[i] - mx);
    __syncthreads();
    if (tid < kS) {
      float al = expf(soft_s[tid] - mx) / den;
      soft_s[tid] = al;
      out[kB * kH + b * kS + tid] = al;  // alpha
    }
    __syncthreads();
    {
      const int h0 = tid;
      float acc = 0.f;
      for (int s2 = 0; s2 < kS; ++s2)
        acc += soft_s[s2] * aload1(&sent_hs[((size_t)b * kS + s2) * kH + h0]);
      out[b * kH + h0] = acc;  // context
    }
  }
}

extern "C" void kernel_launch(void* const* d_in, const int* in_sizes, int n_in,
                              void* d_out, int out_size, void* d_ws, size_t ws_size,
                              hipStream_t stream) {
  (void)in_sizes; (void)n_in; (void)out_size; (void)ws_size;
  const int* captions = (const int*)d_in[0];
  const int* masks = (const int*)d_in[1];
  const float* embed_W = (const float*)d_in[2];
  const float* w_Wih = (const float*)d_in[3];
  const float* w_Whh = (const float*)d_in[4];
  const float* w_bih = (const float*)d_in[5];
  const float* w_bhh = (const float*)d_in[6];
  const float* s_Wih = (const float*)d_in[7];
  const float* s_Whh = (const float*)d_in[8];
  const float* s_bih = (const float*)d_in[9];
  const float* s_bhh = (const float*)d_in[10];
  const float* wa_Wk = (const float*)d_in[11];
  const float* wa_Wv = (const float*)d_in[12];
  const float* sa_Wk = (const float*)d_in[13];
  const float* sa_Wv = (const float*)d_in[14];
  float* out = (float*)d_out;
  float* ws = (float*)d_ws;

  void* args[] = {&captions, &masks, &embed_W, &w_Wih, &w_Whh, &w_bih, &w_bhh,
                  &s_Wih, &s_Whh, &s_bih, &s_bhh, &wa_Wk, &wa_Wv, &sa_Wk, &sa_Wv,
                  &out, &ws};
  hipLaunchCooperativeKernel((void*)ha_kernel, dim3(NWG), dim3(NTH), args, 0, stream);
}

// Round 7
// 25082.085 us; speedup vs baseline: 1.2994x; 1.2994x over previous
//
#include <hip/hip_runtime.h>
#include <hip/hip_cooperative_groups.h>
#include <math.h>

namespace cg = cooperative_groups;

constexpr int kB = 64, kS = 24, kT = 96, kE = 256, kH = 512, kA = 512;
constexpr int NWG = 256, NTH = 512;
constexpr int NG = 8, GWG = 32, GB = 8;   // groups, WGs/group, batches/group
constexpr int WHP = 516;   // whh LDS row stride
constexpr int HSP = 580;   // hstage/parts row stride (580%32==4 -> b-spread)
constexpr int EMP = 264;   // embed LDS row stride
constexpr int EMB0 = 4640; // embed base inside uni (after hstage/parts 4634 max)
constexpr int ATP = 516;   // attention staging stride (16B-aligned)

// ws layout (floats)
constexpr int OFF_PUB = 0;                       // [2][NG][GWG*128] = 65536
constexpr int OFF_SH  = OFF_PUB + 2 * NG * GWG * 128;
constexpr int OFF_HS  = OFF_SH + 2 * kB * kH;
constexpr int OFF_Z   = OFF_HS + kB * kT * kH;
constexpr int OFF_CTX = OFF_Z + kB * kT;
constexpr int OFF_SHS = OFF_CTX + kB * kH;
constexpr int OFF_Z2  = OFF_SHS + kB * kS * kH;
constexpr int OFF_FLG = (OFF_Z2 + kB * kS + 31) & ~31;
// inside flag block (uints): [0,8192) flags (grp*32+r)*32; [8192,8448) cnt x*32;
// [8448,8704) tst flag grp*32; [8704,8960) tst data grp*32; [8960,9216) verdicts grp*32+r

typedef float f4v __attribute__((ext_vector_type(4)));

__device__ __forceinline__ float sigmoidf(float x) { return 1.0f / (1.0f + expf(-x)); }
__device__ __forceinline__ float dot4(float4 a, float4 b) {
  return a.x * b.x + a.y * b.y + a.z * b.z + a.w * b.w;
}
// ---- agent-scope (MALL) ops ----
__device__ __forceinline__ float2 aload2(const float* p) {
  unsigned long long u = __hip_atomic_load((const unsigned long long*)p,
                                           __ATOMIC_RELAXED, __HIP_MEMORY_SCOPE_AGENT);
  union { unsigned long long u; float2 f; } cv; cv.u = u;
  return cv.f;
}
__device__ __forceinline__ float aload1(const float* p) {
  return __hip_atomic_load(p, __ATOMIC_RELAXED, __HIP_MEMORY_SCOPE_AGENT);
}
__device__ __forceinline__ void astore(float* p, float v) {
  __hip_atomic_store(p, v, __ATOMIC_RELAXED, __HIP_MEMORY_SCOPE_AGENT);
}
__device__ __forceinline__ unsigned aloadu(const unsigned* p) {
  return __hip_atomic_load(p, __ATOMIC_RELAXED, __HIP_MEMORY_SCOPE_AGENT);
}
__device__ __forceinline__ void astoreu(unsigned* p, unsigned v) {
  __hip_atomic_store(p, v, __ATOMIC_RELAXED, __HIP_MEMORY_SCOPE_AGENT);
}
// ---- L2-scope (intra-XCD) ops: bypass L1 (sc0), served by local L2 ----
__device__ __forceinline__ unsigned l2_loadu(const unsigned* p) {
  unsigned r;
  asm volatile("global_load_dword %0, %1, off sc0\n\ts_waitcnt vmcnt(0)"
               : "=v"(r) : "v"(p) : "memory");
  return r;
}
__device__ __forceinline__ float l2_load1(const float* p) {
  float r;
  asm volatile("global_load_dword %0, %1, off sc0\n\ts_waitcnt vmcnt(0)"
               : "=v"(r) : "v"(p) : "memory");
  return r;
}
__device__ __forceinline__ float2 l2_load2(const float* p) {
  float2 r;
  asm volatile("global_load_dwordx2 %0, %1, off sc0\n\ts_waitcnt vmcnt(0)"
               : "=v"(r) : "v"(p) : "memory");
  return r;
}
__device__ __forceinline__ void l2_load8(const float* p, f4v& a, f4v& b) {
  asm volatile("global_load_dwordx4 %0, %2, off sc0\n\t"
               "global_load_dwordx4 %1, %2, off offset:16 sc0\n\t"
               "s_waitcnt vmcnt(0)"
               : "=&v"(a), "=&v"(b) : "v"(p) : "memory");
}
__device__ __forceinline__ void l2_atomic_inc(unsigned* p) {
  unsigned one = 1u;
  asm volatile("global_atomic_add %0, %1, off" :: "v"(p), "v"(one) : "memory");
}

__global__ __launch_bounds__(NTH) void ha_kernel(
    const int* __restrict__ captions, const int* __restrict__ masks,
    const float* __restrict__ embed_W,
    const float* __restrict__ w_Wih, const float* __restrict__ w_Whh,
    const float* __restrict__ w_bih, const float* __restrict__ w_bhh,
    const float* __restrict__ s_Wih, const float* __restrict__ s_Whh,
    const float* __restrict__ s_bih, const float* __restrict__ s_bhh,
    const float* __restrict__ wa_Wk, const float* __restrict__ wa_Wv,
    const float* __restrict__ sa_Wk, const float* __restrict__ sa_Wv,
    float* __restrict__ out, float* __restrict__ ws) {
  cg::grid_group grid = cg::this_grid();
  const int g = blockIdx.x, tid = threadIdx.x;
  const int jj = tid >> 6, c = tid & 63;   // GEMV map: wave=k/E-slice, lane=gate col

  float* pub = ws + OFF_PUB;
  float* sh_buf = ws + OFF_SH;
  float* hs_buf = ws + OFF_HS;
  float* z_buf = ws + OFF_Z;
  float* ctx_ws = ws + OFF_CTX;
  float* sent_hs = ws + OFF_SHS;
  float* z2_buf = ws + OFF_Z2;
  unsigned* flags = (unsigned*)(ws + OFF_FLG);
  unsigned* cntp = flags + 8192;
  unsigned* tflagA = flags + 8448;
  unsigned* tdataA = flags + 8704;
  unsigned* verdA = flags + 8960;

  // LDS ~161.8 KB (1 WG/CU)
  __shared__ __align__(16) float whh_s[64 * WHP];   // 132 KB, swizzled
  __shared__ __align__(16) float uni[6752];         // hstage|parts|embed|attn union
  __shared__ float bias_s[64];
  __shared__ float c_s[16][8], hown_s[16][8], sc_s[16][8];
  __shared__ unsigned mbits[24];
  __shared__ float soft_s[96], red_s[96];
  __shared__ int ibuf[4];

  // ---- init zeros (before ranking) ----
  {
    int idx = g * NTH + tid;
    if (idx < 2 * kB * kH) sh_buf[idx] = 0.f;
  }
  if (g == 0)
    for (int idx = tid; idx < 9216; idx += NTH) flags[idx] = 0u;
  grid.sync();

  // ---- XCD discovery + ranking ----
  if (tid == 0) {
    unsigned xcc;
    asm volatile("s_getreg_b32 %0, hwreg(20, 0, 32)" : "=s"(xcc));
    xcc &= 7u;
    unsigned slot = atomicAdd(&cntp[xcc * 32], 1u);
    ibuf[0] = (int)xcc; ibuf[1] = (int)slot;
  }
  grid.sync();
  __syncthreads();
  const int myxcc = ibuf[0], myslot = ibuf[1];
  unsigned cnts[8]; int px[9]; px[0] = 0;
  for (int x = 0; x < 8; ++x) { cnts[x] = aloadu(&cntp[x * 32]); px[x + 1] = px[x] + (int)cnts[x]; }
  const int rank = px[myxcc] + myslot;
  const int grp = rank >> 5, r = rank & 31;
  const int B0 = GB * grp;
  bool pure = false;
  for (int x = 0; x < 8; ++x)
    if (px[x] <= grp * 32 && grp * 32 + 32 <= px[x + 1]) pure = true;
  const bool cand = pure && (cnts[myxcc] <= 40u);
  unsigned* myflag = &flags[(grp * GWG + r) * 32];

  auto g_row = [&](int cc) { return (cc >> 4) * kH + 16 * r + (cc & 15); };

  // ---- L2-coherence handshake (bounded; decides l2m per group, no-hang) ----
  unsigned n = 0;
  {
    unsigned* tf = &tflagA[grp * 32];
    unsigned* td = &tdataA[grp * 32];
    int ok = 0;
    if (cand && r == 0 && tid == 0) {
      *td = 0xC0FFEEu;                                  // plain store -> local L2
      asm volatile("s_waitcnt vmcnt(0)" ::: "memory");
      l2_atomic_inc(tf);                                // L2 atomic
    }
    if (cand && tid == 0) {
      for (int it = 0; it < 4096; ++it) {
        if (l2_loadu(tf) >= 1u) { ok = (l2_loadu(td) == 0xC0FFEEu); break; }
        __builtin_amdgcn_s_sleep(2);
      }
    }
    if (tid == 0) {
      astoreu(&verdA[grp * 32 + r], ok ? 1u : 0u);
      asm volatile("s_waitcnt vmcnt(0)" ::: "memory");
      atomicAdd(myflag, 1u);                            // agent arrive, n=1
    }
    n = 1;
    if (tid < GWG) {
      while (aloadu(&flags[(grp * GWG + tid) * 32]) < 1u) __builtin_amdgcn_s_sleep(2);
    }
    __syncthreads();
    if (tid < GWG) red_s[tid] = (float)aloadu(&verdA[grp * 32 + tid]);
    __syncthreads();
    if (tid == 0) {
      int all = 1;
      for (int i = 0; i < GWG; ++i) all &= (red_s[i] != 0.f);
      ibuf[2] = all;
    }
    __syncthreads();
  }
  const bool l2m = (ibuf[2] != 0);

  // ---- mode-dispatched ops ----
  auto mstore1 = [&](float* p, float v) { if (l2m) *p = v; else astore(p, v); };
  auto mload1 = [&](const float* p) { return l2m ? l2_load1(p) : aload1(p); };
  auto mload2 = [&](const float* p) { return l2m ? l2_load2(p) : aload2(p); };
  auto mload8 = [&](const float* p, f4v& a, f4v& b) {
    if (l2m) l2_load8(p, a, b);
    else {
      float2 t0 = aload2(p), t1 = aload2(p + 2), t2 = aload2(p + 4), t3 = aload2(p + 6);
      a = f4v{t0.x, t0.y, t1.x, t1.y}; b = f4v{t2.x, t2.y, t3.x, t3.y};
    }
  };
  auto arrive = [&]() {
    __syncthreads();   // drains all stores (vmcnt) -> visible at coherence point
    if (tid == 0) { if (l2m) l2_atomic_inc(myflag); else atomicAdd(myflag, 1u); }
  };
  auto wait = [&](unsigned nn) {
    if (tid < GWG) {
      const unsigned* fp = &flags[(grp * GWG + tid) * 32];
      if (l2m) { while (l2_loadu(fp) < nn) __builtin_amdgcn_s_sleep(1); }
      else     { while (aloadu(fp) < nn)   __builtin_amdgcn_s_sleep(1); }
    }
    __syncthreads();
  };

  // ---- per-WG weight staging (needs r) ----
  for (int idx = tid; idx < 64 * kH; idx += NTH) {
    const int c2 = idx >> 9, kk = idx & 511;
    whh_s[c2 * WHP + 4 * (((kk >> 2) + 4 * (c2 & 1)) & 127) + (kk & 3)] =
        w_Whh[(size_t)g_row(c2) * kH + kk];
  }
  if (tid < 64) bias_s[tid] = w_bih[g_row(tid)] + w_bhh[g_row(tid)];
  if (tid < 128) {
    c_s[tid >> 3][tid & 7] = 0.f; hown_s[tid >> 3][tid & 7] = 0.f; sc_s[tid >> 3][tid & 7] = 0.f;
  }
  for (int idx = tid; idx < 6752; idx += NTH) uni[idx] = 0.f;   // h(0)=0
  __syncthreads();

  // ---- stagers into hstage (dest: uni[b*HSP + k + 4*(k>>5)]) ----
  auto stage_hst_pub = [&](const float* slab) {   // slab[rr*128 + b*16 + hcl]
    const int lin = tid * 8, rsm = lin >> 7, rem = lin & 127;
    const int b2 = rem >> 4, kk = (rsm << 4) | (rem & 15);
    f4v a, b4; mload8(slab + lin, a, b4);
    const int ho = kk + 4 * (kk >> 5);
    *(f4v*)&uni[b2 * HSP + ho] = a;
    *(f4v*)&uni[b2 * HSP + ho + 4] = b4;
  };
  auto stage_hst_lin = [&](const float* src) {    // src[b*512 + k]
    const int lin = tid * 8, b2 = lin >> 9, kk = lin & 511;
    f4v a, b4; mload8(src + lin, a, b4);
    const int ho = kk + 4 * (kk >> 5);
    *(f4v*)&uni[b2 * HSP + ho] = a;
    *(f4v*)&uni[b2 * HSP + ho + 4] = b4;
  };
  auto stage_emb = [&](int s2, int t2) {
    const int b2 = tid >> 6, ch = tid & 63;
    const int cap = captions[((B0 + b2) * kS + s2) * kT + t2];
    const float4 v = *(const float4*)&embed_W[(size_t)cap * kE + 4 * ch];
    *(float4*)&uni[EMB0 + b2 * EMP + 4 * ch] = v;
  };
  float xp[8];
  auto calc_xp = [&]() {
    const float* wr = w_Wih + (size_t)g_row(c) * kE + 32 * jj;
    const float* eb = &uni[EMB0];
#pragma unroll
    for (int b2 = 0; b2 < 8; ++b2) xp[b2] = 0.f;
#pragma unroll
    for (int v = 0; v < 8; ++v) {
      const float4 w = *(const float4*)&wr[4 * v];
#pragma unroll
      for (int b2 = 0; b2 < 8; ++b2)
        xp[b2] += dot4(w, *(const float4*)&eb[b2 * EMP + 32 * jj + 4 * v]);
    }
  };

  stage_emb(0, 0);
  __syncthreads();
  calc_xp();

  int gstep = 0;
  for (int s = 0; s < kS; ++s) {
    if (tid < 24) {   // pack masks as bits
      const int b2 = tid / 3, w2 = tid % 3;
      unsigned bits = 0u;
      const int base = ((B0 + b2) * kS + s) * kT + 32 * w2;
      for (int j = 0; j < 32; ++j) bits |= (masks[base + j] ? 1u : 0u) << j;
      mbits[b2 * 3 + w2] = bits;
    }
    if (s > 0) stage_hst_pub(pub + ((size_t)((gstep & 1) * NG + grp)) * 4096);
    __syncthreads();

    // ============ word LSTM: 96 steps, one group barrier each ============
    for (int t = 0; t < kT; ++t, ++gstep) {
      float* pubw = pub + ((size_t)(((gstep + 1) & 1) * NG + grp)) * 4096;

      // GEMV: acc[b] = xp + Whh(LDS) . h(LDS broadcast)
      float acc[8];
#pragma unroll
      for (int b2 = 0; b2 < 8; ++b2) acc[b2] = xp[b2];
      {
        const int swc = 4 * (c & 1);
        const float* wrow = &whh_s[c * WHP];
#pragma unroll 4
        for (int u = 0; u < 16; ++u) {
          const int q = 16 * jj + u;
          const float4 w = *(const float4*)&wrow[4 * ((q + swc) & 127)];
          const int hoff = 4 * q + 4 * (q >> 3);
#pragma unroll
          for (int b2 = 0; b2 < 8; ++b2)
            acc[b2] += dot4(w, *(const float4*)&uni[b2 * HSP + hoff]);
        }
      }
      __syncthreads();   // hstage reads done before parts alias write
#pragma unroll
      for (int b2 = 0; b2 < 8; ++b2) uni[jj * HSP + c * 9 + b2] = acc[b2];
      __syncthreads();
      // fused reduce + cell + publish
      float hsv = 0.f;
      if (tid < 128) {
        const int hcl = tid >> 3, b2 = tid & 7;
        float gg4[4];
#pragma unroll
        for (int g2 = 0; g2 < 4; ++g2) {
          const int c2 = g2 * 16 + hcl;
          float sum = bias_s[c2];
#pragma unroll
          for (int j = 0; j < 8; ++j) sum += uni[j * HSP + c2 * 9 + b2];
          gg4[g2] = sum;
        }
        const float cold = c_s[hcl][b2];
        const float c2v = sigmoidf(gg4[1]) * cold + sigmoidf(gg4[0]) * tanhf(gg4[2]);
        const float h2 = sigmoidf(gg4[3]) * tanhf(c2v);
        const int m = (mbits[b2 * 3 + (t >> 5)] >> (t & 31)) & 1;
        const float cn = m ? c2v : cold;
        const float hn = m ? h2 : hown_s[hcl][b2];
        c_s[hcl][b2] = cn; hown_s[hcl][b2] = hn;
        mstore1(&pubw[r * 128 + b2 * 16 + hcl], hn);
        hsv = m ? h2 : 0.f;
      }
      ++n;
      arrive();
      // ---- cover (runs inside the barrier window) ----
      if (tid < 128) {
        const int hcl = tid >> 3, b2 = tid & 7;
        mstore1(&hs_buf[((size_t)(B0 + b2) * kT + t) * kH + 16 * r + hcl], hsv);
      }
      int ns = s, nt = t + 1; bool have = true;
      if (nt == kT) { nt = 0; ns = s + 1; if (ns == kS) have = false; }
      if (have) stage_emb(ns, nt);
      __syncthreads();
      if (have) calc_xp();
      wait(n);
      stage_hst_pub(pubw);
      __syncthreads();
    }

    ++n; arrive(); wait(n);   // phase 1: hs drained everywhere

    // ============ word attention: z[b,t] ============
    {
      const int ab = r >> 2, t0 = (r & 3) * 24;
      const int bg = B0 + ab;
      for (int half = 0; half < 2; ++half) {
        const int tb = t0 + half * 12;
        for (int idx = tid; idx < 12 * 256; idx += NTH) {
          const int pp = idx >> 8, hh2 = (idx & 255) * 2;
          float2 v = mload2(&hs_buf[((size_t)bg * kT + tb + pp) * kH + hh2]);
          *(float2*)&uni[pp * ATP + hh2] = v;
        }
        __syncthreads();
        float dacc[12];
#pragma unroll
        for (int p = 0; p < 12; ++p) dacc[p] = 0.f;
        const float4* __restrict__ wk = (const float4*)(wa_Wk + (size_t)tid * kH);
        for (int k = 0; k < kH / 4; ++k) {
          const float4 w = wk[k];
#pragma unroll
          for (int p = 0; p < 12; ++p)
            dacc[p] += dot4(w, *(const float4*)&uni[p * ATP + 4 * k]);
        }
        const float wv = wa_Wv[tid];
        const int ln = tid & 63, wid = tid >> 6;
#pragma unroll
        for (int p = 0; p < 12; ++p) {
          float v = wv * tanhf(dacc[p]);
          v += __shfl_down(v, 32); v += __shfl_down(v, 16); v += __shfl_down(v, 8);
          v += __shfl_down(v, 4);  v += __shfl_down(v, 2);  v += __shfl_down(v, 1);
          if (ln == 0) red_s[wid * 12 + p] = v;
        }
        __syncthreads();
        if (tid < 12) {
          float sum = 0.f;
#pragma unroll
          for (int w = 0; w < 8; ++w) sum += red_s[w * 12 + tid];
          mstore1(&z_buf[bg * kT + tb + tid], sum);
        }
        __syncthreads();
      }
    }
    ++n; arrive(); wait(n);

    // ============ softmax over T + ctx ============
    if (r < GB) {
      const int b2 = B0 + r;
      if (tid < kT) soft_s[tid] = mload1(&z_buf[b2 * kT + tid]);
      __syncthreads();
      float mx = -1e30f;
      for (int i = 0; i < kT; ++i) mx = fmaxf(mx, soft_s[i]);
      float den = 0.f;
      for (int i = 0; i < kT; ++i) den += expf(soft_s[i] - mx);
      __syncthreads();
      if (tid < kT) soft_s[tid] = expf(soft_s[tid] - mx) / den;
      __syncthreads();
      {
        const int h0 = tid;
        float a0 = 0.f, a1 = 0.f, a2 = 0.f, a3 = 0.f;
        for (int tt = 0; tt < kT; tt += 4) {
          a0 += soft_s[tt + 0] * mload1(&hs_buf[((size_t)b2 * kT + tt + 0) * kH + h0]);
          a1 += soft_s[tt + 1] * mload1(&hs_buf[((size_t)b2 * kT + tt + 1) * kH + h0]);
          a2 += soft_s[tt + 2] * mload1(&hs_buf[((size_t)b2 * kT + tt + 2) * kH + h0]);
          a3 += soft_s[tt + 3] * mload1(&hs_buf[((size_t)b2 * kT + tt + 3) * kH + h0]);
        }
        mstore1(&ctx_ws[b2 * kH + h0], (a0 + a1) + (a2 + a3));
      }
    }
    ++n; arrive(); wait(n);

    // ============ sentence LSTM (two-pass streamed GEMV) ============
    {
      float acc[8];
#pragma unroll
      for (int b2 = 0; b2 < 8; ++b2) acc[b2] = 0.f;
      stage_hst_lin(ctx_ws + B0 * kH);   // pass A: x = ctx
      __syncthreads();
      {
        const float* wA = s_Wih + (size_t)g_row(c) * kH + 64 * jj;
#pragma unroll 8
        for (int u = 0; u < 16; ++u) {
          const float4 w = *(const float4*)&wA[4 * u];
          const int q = 16 * jj + u;
          const int hoff = 4 * q + 4 * (q >> 3);
#pragma unroll
          for (int b2 = 0; b2 < 8; ++b2)
            acc[b2] += dot4(w, *(const float4*)&uni[b2 * HSP + hoff]);
        }
      }
      __syncthreads();
      stage_hst_lin(sh_buf + (s & 1) * kB * kH + B0 * kH);   // pass B: h = sh
      __syncthreads();
      {
        const float* wB = s_Whh + (size_t)g_row(c) * kH + 64 * jj;
#pragma unroll 8
        for (int u = 0; u < 16; ++u) {
          const float4 w = *(const float4*)&wB[4 * u];
          const int q = 16 * jj + u;
          const int hoff = 4 * q + 4 * (q >> 3);
#pragma unroll
          for (int b2 = 0; b2 < 8; ++b2)
            acc[b2] += dot4(w, *(const float4*)&uni[b2 * HSP + hoff]);
        }
      }
      __syncthreads();
#pragma unroll
      for (int b2 = 0; b2 < 8; ++b2) uni[jj * HSP + c * 9 + b2] = acc[b2];
      __syncthreads();
      if (tid < 128) {
        const int hcl = tid >> 3, b2 = tid & 7;
        float gg4[4];
#pragma unroll
        for (int g2 = 0; g2 < 4; ++g2) {
          const int c2 = g2 * 16 + hcl;
          const int row = g_row(c2);
          float sum = s_bih[row] + s_bhh[row];
#pragma unroll
          for (int j = 0; j < 8; ++j) sum += uni[j * HSP + c2 * 9 + b2];
          gg4[g2] = sum;
        }
        const float c2v = sigmoidf(gg4[1]) * sc_s[hcl][b2] + sigmoidf(gg4[0]) * tanhf(gg4[2]);
        const float h2 = sigmoidf(gg4[3]) * tanhf(c2v);
        sc_s[hcl][b2] = c2v;
        const int col = 16 * r + hcl;
        mstore1(&sh_buf[((s + 1) & 1) * kB * kH + (B0 + b2) * kH + col], h2);
        mstore1(&sent_hs[((size_t)(B0 + b2) * kS + s) * kH + col], h2);
      }
    }
    ++n; arrive(); wait(n);
  }

  // ============ final attention over S ============
  {
    const int pair0 = r * 6;
    for (int idx = tid; idx < 6 * 256; idx += NTH) {
      const int pp = idx >> 8, hh2 = (idx & 255) * 2;
      const int pr = pair0 + pp;
      float2 v = mload2(&sent_hs[((size_t)(B0 + pr / kS) * kS + pr % kS) * kH + hh2]);
      *(float2*)&uni[pp * ATP + hh2] = v;
    }
    __syncthreads();
    float dacc[6];
#pragma unroll
    for (int p = 0; p < 6; ++p) dacc[p] = 0.f;
    const float4* __restrict__ wk = (const float4*)(sa_Wk + (size_t)tid * kH);
    for (int k = 0; k < kH / 4; ++k) {
      const float4 w = wk[k];
#pragma unroll
      for (int p = 0; p < 6; ++p)
        dacc[p] += dot4(w, *(const float4*)&uni[p * ATP + 4 * k]);
    }
    const float wv = sa_Wv[tid];
    const int ln = tid & 63, wid = tid >> 6;
#pragma unroll
    for (int p = 0; p < 6; ++p) {
      float v = wv * tanhf(dacc[p]);
      v += __shfl_down(v, 32); v += __shfl_down(v, 16); v += __shfl_down(v, 8);
      v += __shfl_down(v, 4);  v += __shfl_down(v, 2);  v += __shfl_down(v, 1);
      if (ln == 0) red_s[wid * 6 + p] = v;
    }
    __syncthreads();
    if (tid < 6) {
      float sum = 0.f;
#pragma unroll
      for (int w = 0; w < 8; ++w) sum += red_s[w * 6 + tid];
      mstore1(&z2_buf[B0 * kS + pair0 + tid], sum);
    }
  }
  ++n; arrive(); wait(n);

  // ============ final softmax + outputs ============
  if (r < GB) {
    const int b2 = B0 + r;
    if (tid < kS) soft_s[tid] = mload1(&z2_buf[b2 * kS + tid]);
    __syncthreads();
    float mx = -1e30f;
    for (int i = 0; i < kS; ++i) mx = fmaxf(mx, soft_s[i]);
    float den = 0.f;
    for (int i = 0; i < kS; ++i) den += expf(soft_s[i] - mx);
    __syncthreads();
    if (tid < kS) {
      const float al = expf(soft_s[tid] - mx) / den;
      soft_s[tid] = al;
      out[kB * kH + b2 * kS + tid] = al;   // alpha
    }
    __syncthreads();
    {
      const int h0 = tid;
      float acc2 = 0.f;
      for (int s2 = 0; s2 < kS; ++s2)
        acc2 += soft_s[s2] * mload1(&sent_hs[((size_t)b2 * kS + s2) * kH + h0]);
      out[b2 * kH + h0] = acc2;   // context
    }
  }
}

extern "C" void kernel_launch(void* const* d_in, const int* in_sizes, int n_in,
                              void* d_out, int out_size, void* d_ws, size_t ws_size,
                              hipStream_t stream) {
  (void)in_sizes; (void)n_in; (void)out_size; (void)ws_size;
  const int* captions = (const int*)d_in[0];
  const int* masks = (const int*)d_in[1];
  const float* embed_W = (const float*)d_in[2];
  const float* w_Wih = (const float*)d_in[3];
  const float* w_Whh = (const float*)d_in[4];
  const float* w_bih = (const float*)d_in[5];
  const float* w_bhh = (const float*)d_in[6];
  const float* s_Wih = (const float*)d_in[7];
  const float* s_Whh = (const float*)d_in[8];
  const float* s_bih = (const float*)d_in[9];
  const float* s_bhh = (const float*)d_in[10];
  const float* wa_Wk = (const float*)d_in[11];
  const float* wa_Wv = (const float*)d_in[12];
  const float* sa_Wk = (const float*)d_in[13];
  const float* sa_Wv = (const float*)d_in[14];
  float* out = (float*)d_out;
  float* ws = (float*)d_ws;

  void* args[] = {&captions, &masks, &embed_W, &w_Wih, &w_Whh, &w_bih, &w_bhh,
                  &s_Wih, &s_Whh, &s_bih, &s_bhh, &wa_Wk, &wa_Wv, &sa_Wk, &sa_Wv,
                  &out, &ws};
  hipLaunchCooperativeKernel((void*)ha_kernel, dim3(NWG), dim3(NTH), args, 0, stream);
}